// Round 3
// baseline (155.554 us; speedup 1.0000x reference)
//
#include <hip/hip_runtime.h>
#include <hip/hip_bf16.h>

// SAGAN attention B=8, C=64, N=4096, Cr=8.
// prep: x -> (LDS transpose) -> W GEMM -> Qp, Kp, Vf(fragment-linear)
// attn: barrier-free flash loop; V fragments loaded straight from global (L2),
//       P transposed through wave-private double-buffered fragment-linear LDS.
// combine: sum 4 j-split partials, normalize, gamma*o + x.
//
// ws layout (bytes):
//   [0    , 0.5M)   Qp [b][n][8]  bf16  (Wf.x * log2e)
//   [0.5M , 1M  )   Kp [b][n][8]  bf16
//   [1M   , 5M  )   Vf [b][jt64][ch2][ks4][lane64][e8] bf16  (B-frag linear, 8KB/slab)
//   [5M   , 5M+64)  zero block
//   [5M+1K, 5.5M)   Lpart [js4][b][n] fp32
//   [6M   , 22M )   Opart [js4][b][n][c] bf16

#define N_ 4096
#define LOG2E 1.4426950408889634f

typedef __attribute__((ext_vector_type(8)))  __bf16 bf16x8;
typedef __attribute__((ext_vector_type(4)))  float  f32x4;
typedef __attribute__((ext_vector_type(16))) float  f32x16;

union U16B { uint4 u; bf16x8 b; };

static __device__ inline uint pack_bf2(float a, float b) {
  __hip_bfloat162 h = __float22bfloat162_rn(make_float2(a, b));
  uint r; __builtin_memcpy(&r, &h, 4); return r;
}
static __device__ inline ushort f2bf(float a) {
  __hip_bfloat16 h = __float2bfloat16(a);
  ushort r; __builtin_memcpy(&r, &h, 2); return r;
}
static __device__ inline float bflo(uint u) {
  uint v = u << 16; float f; __builtin_memcpy(&f, &v, 4); return f;
}
static __device__ inline float bfhi(uint u) {
  uint v = u & 0xffff0000u; float f; __builtin_memcpy(&f, &v, 4); return f;
}

// ---------------- pass 1: fused transpose + projection ----------------
__global__ __launch_bounds__(256) void prep_kernel(
    const float* __restrict__ x,  const float* __restrict__ Wf,
    const float* __restrict__ Wg, const float* __restrict__ Wh,
    ushort* __restrict__ Qp, ushort* __restrict__ Kp,
    ushort* __restrict__ Vf, uint* __restrict__ zb)
{
  __shared__ __align__(16) char smem[37376];
  float*  T   = (float*)smem;              // 64x65 fp32 x-tile (later reused as Vt 8KB)
  ushort* xTl = (ushort*)(smem + 16640);   // 64n x 72c bf16
  ushort* Wb  = (ushort*)(smem + 25856);   // 80 x 72 bf16
  const int b = blockIdx.y, n0 = blockIdx.x * 64, tid = threadIdx.x;
  if (blockIdx.x == 0 && b == 0 && tid < 16) zb[tid] = 0u;

  { // stage x tile (coalesced by n)
    const int nl = tid & 63, cw = tid >> 6;
#pragma unroll
    for (int i = 0; i < 16; ++i) {
      const int c = i * 4 + cw;
      T[c * 65 + nl] = x[((size_t)(b * 64 + c)) * N_ + n0 + nl];
    }
  }
  { // stage weights (wave-uniform rows)
#pragma unroll
    for (int i = 0; i < 20; ++i) {
      const int e = i * 256 + tid;
      const int row = e >> 6, col = e & 63;
      float v;
      if (row < 8)       v = Wf[row * 64 + col] * LOG2E;
      else if (row < 16) v = Wg[(row - 8) * 64 + col];
      else               v = Wh[(row - 16) * 64 + col];
      Wb[row * 72 + col] = f2bf(v);
    }
  }
  __syncthreads();
  { // transpose to xTl [n][c] bf16
    const int n = tid >> 2, cq = (tid & 3) * 16;
    uint o[8];
#pragma unroll
    for (int j = 0; j < 8; ++j)
      o[j] = pack_bf2(T[(cq + 2 * j) * 65 + n], T[(cq + 2 * j + 1) * 65 + n]);
    *(uint4*)(xTl + n * 72 + cq)     = make_uint4(o[0], o[1], o[2], o[3]);
    *(uint4*)(xTl + n * 72 + cq + 8) = make_uint4(o[4], o[5], o[6], o[7]);
  }
  __syncthreads();

  const int l = tid & 63, w = tid >> 6, l15 = l & 15, lq = l >> 4;
  const int nn = w * 16 + l15;
  U16B bf0, bf1;
  bf0.u = *(const uint4*)(xTl + nn * 72 + lq * 8);
  bf1.u = *(const uint4*)(xTl + nn * 72 + 32 + lq * 8);
  f32x4 acc[5];
#pragma unroll
  for (int mt = 0; mt < 5; ++mt) {
    U16B a0, a1;
    a0.u = *(const uint4*)(Wb + (mt * 16 + l15) * 72 + lq * 8);
    a1.u = *(const uint4*)(Wb + (mt * 16 + l15) * 72 + 32 + lq * 8);
    f32x4 c0 = __builtin_amdgcn_mfma_f32_16x16x32_bf16(a0.b, bf0.b, (f32x4){0.f,0.f,0.f,0.f}, 0, 0, 0);
    acc[mt]  = __builtin_amdgcn_mfma_f32_16x16x32_bf16(a1.b, bf1.b, c0, 0, 0, 0);
  }
  const int n = n0 + nn;
  { // rows 0-7 -> Q, 8-15 -> K  (C: col=n=l15, row=lq*4+r)
    uint lo = pack_bf2(acc[0][0], acc[0][1]);
    uint hi = pack_bf2(acc[0][2], acc[0][3]);
    ushort* dst = (lq < 2 ? Qp : Kp) + ((size_t)(b * N_ + n)) * 8 + (lq & 1) * 4;
    *(uint2*)dst = make_uint2(lo, hi);
  }
  // V -> fragment-linear LDS tile (overwrites T; safe: T dead after 2nd barrier)
  ushort* Vt = (ushort*)smem;
#pragma unroll
  for (int mt = 1; mt < 5; ++mt)
#pragma unroll
    for (int r = 0; r < 4; ++r) {
      const int c = (mt - 1) * 16 + lq * 4 + r;
      Vt[(c >> 5) * 2048 + w * 512 + ((l15 >> 3) * 32 + (c & 31)) * 8 + (l15 & 7)]
          = f2bf(acc[mt][r]);
    }
  __syncthreads();
  const uint4* src = (const uint4*)Vt;
  uint4* dst = (uint4*)(Vf + ((size_t)(b * 64 + blockIdx.x)) * 4096);
  dst[tid]       = src[tid];
  dst[256 + tid] = src[256 + tid];
}

// ---------------- pass 2: barrier-free flash attention, j-split x4 ----------------
// grid (32 qtile, 4 js, 8 b), 256 thr, 32 q/wave, 16 j-tiles of 64 per block.
// LDS: P double-buffered per wave: 4 waves x 2 x 4KB = 32KB. No __syncthreads.
__global__ __launch_bounds__(256) void attn_kernel(
    const ushort* __restrict__ Qp, const ushort* __restrict__ Kp,
    const ushort* __restrict__ Vf, const uint* __restrict__ zb,
    ushort* __restrict__ Opart, float* __restrict__ Lpart)
{
  __shared__ __align__(16) char smem[32768];
  const int b = blockIdx.z, js = blockIdx.y, q0 = blockIdx.x * 128;
  const int tid = threadIdx.x, w = tid >> 6, l = tid & 63;
  const int l15 = l & 15, lq = l >> 4, l31 = l & 31, lq1 = l >> 5;
  const int qw = q0 + w * 32;
  const uint4* zb16 = (const uint4*)zb;

  U16B qf0, qf1;   // B-frags; k>=8 garbage is killed by A-side zeros
  qf0.u = *(const uint4*)(Qp + ((size_t)(b * N_ + qw + l15)) * 8);
  qf1.u = *(const uint4*)(Qp + ((size_t)(b * N_ + qw + 16 + l15)) * 8);

  const int pconst = (lq >> 1) * 512 + l15 * 16 + (lq & 1) * 8;
  const int jt0 = js * 16;

  U16B kf[4], kfn[4];
#pragma unroll
  for (int t = 0; t < 4; ++t)
    kf[t].u = (l < 16)
        ? *(const uint4*)(Kp + ((size_t)(b * N_ + jt0 * 64 + t * 16 + l15)) * 8)
        : *zb16;

  f32x16 O0 = {0,0,0,0,0,0,0,0,0,0,0,0,0,0,0,0};
  f32x16 O1 = {0,0,0,0,0,0,0,0,0,0,0,0,0,0,0,0};
  float L0 = 0.f, L1 = 0.f;

  for (int jt = 0; jt < 16; ++jt) {
    if (jt < 15) {  // register prefetch of next K fragments
      const size_t kr = (size_t)(b * N_ + (jt0 + jt + 1) * 64);
#pragma unroll
      for (int t = 0; t < 4; ++t)
        kfn[t].u = (l < 16) ? *(const uint4*)(Kp + (kr + t * 16 + l15) * 8) : *zb16;
    }
    // S^T = K * Q^T (A = K, m=j, d zero-padded to 32; B = Q, n=q)
    f32x4 St0[4], St1[4];
#pragma unroll
    for (int t = 0; t < 4; ++t) {
      St0[t] = __builtin_amdgcn_mfma_f32_16x16x32_bf16(kf[t].b, qf0.b, (f32x4){0.f,0.f,0.f,0.f}, 0, 0, 0);
      St1[t] = __builtin_amdgcn_mfma_f32_16x16x32_bf16(kf[t].b, qf1.b, (f32x4){0.f,0.f,0.f,0.f}, 0, 0, 0);
    }
    // exp2, denominator partials, pack -> fragment-linear P (parity buffer)
    char* Pp = smem + (((w << 1) | (jt & 1)) << 12);
#pragma unroll
    for (int u = 0; u < 2; ++u)
#pragma unroll
      for (int t = 0; t < 4; ++t) {
        const f32x4 s = u ? St1[t] : St0[t];
        const float p0 = __builtin_amdgcn_exp2f(s[0]);
        const float p1 = __builtin_amdgcn_exp2f(s[1]);
        const float p2 = __builtin_amdgcn_exp2f(s[2]);
        const float p3 = __builtin_amdgcn_exp2f(s[3]);
        const float ps = (p0 + p1) + (p2 + p3);
        if (u) L1 += ps; else L0 += ps;
        *(uint2*)(Pp + t * 1024 + u * 256 + pconst)
            = make_uint2(pack_bf2(p0, p1), pack_bf2(p2, p3));
      }
    // O += P * V ; V fragments straight from global (fragment-linear, coalesced)
    const ushort* Vb = Vf + ((size_t)(b * 64 + jt0 + jt)) * 4096;
#pragma unroll
    for (int ks = 0; ks < 4; ++ks) {
      U16B pa; pa.u = *(const uint4*)(Pp + ks * 1024 + l * 16);
      U16B v0; v0.u = *(const uint4*)(Vb + ks * 512 + l * 8);
      O0 = __builtin_amdgcn_mfma_f32_32x32x16_bf16(pa.b, v0.b, O0, 0, 0, 0);
      U16B v1; v1.u = *(const uint4*)(Vb + 2048 + ks * 512 + l * 8);
      O1 = __builtin_amdgcn_mfma_f32_32x32x16_bf16(pa.b, v1.b, O1, 0, 0, 0);
    }
    if (jt < 15) {
#pragma unroll
      for (int t = 0; t < 4; ++t) kf[t] = kfn[t];
    }
  }

  // partial denominators
  L0 += __shfl_xor(L0, 16); L0 += __shfl_xor(L0, 32);
  L1 += __shfl_xor(L1, 16); L1 += __shfl_xor(L1, 32);
  float* Lp = Lpart + ((size_t)(js * 8 + b)) * N_;
  if (lq == 0) Lp[qw + l15] = L0;
  if (lq == 1) Lp[qw + 16 + l15] = L1;

  // partial O (bf16): C rows q' = (reg&3) + 8*(reg>>2) + 4*lq1, col c = l31
  ushort* Op = Opart + (((size_t)(js * 8 + b)) * N_ + qw) * 64;
#pragma unroll
  for (int g = 0; g < 4; ++g)
#pragma unroll
    for (int rr = 0; rr < 4; ++rr) {
      const int qp = rr + 8 * g + 4 * lq1;
      Op[qp * 64 + l31]      = f2bf(O0[g * 4 + rr]);
      Op[qp * 64 + 32 + l31] = f2bf(O1[g * 4 + rr]);
    }
}

// ---------------- pass 3: combine partials + normalize + gamma*o + x ----------------
__global__ __launch_bounds__(256) void combine_kernel(
    const ushort* __restrict__ Opart, const float* __restrict__ Lpart,
    const float* __restrict__ x, const float* __restrict__ gamma,
    float* __restrict__ out)
{
  __shared__ float T[64 * 65];
  const int b = blockIdx.y, n0 = blockIdx.x * 64, tid = threadIdx.x;
  float acc[16];
#pragma unroll
  for (int e = 0; e < 16; ++e) acc[e] = 0.f;
#pragma unroll
  for (int js = 0; js < 4; ++js) {
    const ushort* Op = Opart + (((size_t)(js * 8 + b)) * N_ + n0) * 64 + tid * 16;
    uint4 a = *(const uint4*)Op;
    uint4 c2 = *(const uint4*)(Op + 8);
    acc[0] += bflo(a.x);  acc[1] += bfhi(a.x);  acc[2] += bflo(a.y);  acc[3] += bfhi(a.y);
    acc[4] += bflo(a.z);  acc[5] += bfhi(a.z);  acc[6] += bflo(a.w);  acc[7] += bfhi(a.w);
    acc[8] += bflo(c2.x); acc[9] += bfhi(c2.x); acc[10]+= bflo(c2.y); acc[11]+= bfhi(c2.y);
    acc[12]+= bflo(c2.z); acc[13]+= bfhi(c2.z); acc[14]+= bflo(c2.w); acc[15]+= bfhi(c2.w);
  }
  const int nr = tid >> 2, c0 = (tid & 3) * 16;
#pragma unroll
  for (int e = 0; e < 16; ++e) T[nr * 65 + c0 + e] = acc[e];
  __syncthreads();
  const float g = gamma[0];
  const int n = tid & 63, cq = (tid >> 6) * 16;
  float Ls = 0.f;
#pragma unroll
  for (int js = 0; js < 4; ++js) Ls += Lpart[((size_t)(js * 8 + b)) * N_ + n0 + n];
  const float gr = g / Ls;
#pragma unroll
  for (int i = 0; i < 16; ++i) {
    const int c = cq + i;
    const size_t oi = ((size_t)(b * 64 + c)) * N_ + n0 + n;
    out[oi] = gr * T[n * 65 + c] + x[oi];
  }
}

extern "C" void kernel_launch(void* const* d_in, const int* in_sizes, int n_in,
                              void* d_out, int out_size, void* d_ws, size_t ws_size,
                              hipStream_t stream) {
  const float* x     = (const float*)d_in[0];
  const float* Wf    = (const float*)d_in[1];
  const float* Wg    = (const float*)d_in[2];
  const float* Wh    = (const float*)d_in[3];
  const float* gamma = (const float*)d_in[4];
  float* out = (float*)d_out;
  char* ws = (char*)d_ws;

  ushort* Qp    = (ushort*)(ws);
  ushort* Kp    = (ushort*)(ws + 512 * 1024);
  ushort* Vf    = (ushort*)(ws + 1024 * 1024);            // 4 MB
  uint*   zb    = (uint*)  (ws + 5 * 1024 * 1024);
  float*  Lpart = (float*) (ws + 5 * 1024 * 1024 + 1024); // 512 KB
  ushort* Opart = (ushort*)(ws + 6 * 1024 * 1024);        // 16 MB

  prep_kernel   <<<dim3(64, 8),    256, 0, stream>>>(x, Wf, Wg, Wh, Qp, Kp, Vf, zb);
  attn_kernel   <<<dim3(32, 4, 8), 256, 0, stream>>>(Qp, Kp, Vf, zb, Opart, Lpart);
  combine_kernel<<<dim3(64, 8),    256, 0, stream>>>(Opart, Lpart, x, gamma, out);
}

// Round 4
// 114.243 us; speedup vs baseline: 1.3616x; 1.3616x over previous
//
#include <hip/hip_runtime.h>
#include <hip/hip_bf16.h>

// SAGAN attention B=8, C=64, N=4096, Cr=8.
// prep: x -> (LDS transpose) -> W GEMM -> Qp, Kp, Vf (pi-permuted fragment-linear)
// attn: 64 q/wave, QK via 32x32x16 (d zero-padded 8->16) whose C-layout feeds PV
//       A-frags directly in-register (pi-permuted j); V in block-shared LDS,
//       double-buffered, register-prefetched, one barrier/tile. j-split x4.
// combine: sum partials, normalize, gamma*o + x.
//
// ws layout (bytes):
//   [0    , 0.5M)  Qp [b][n][8] bf16 (Wf.x * log2e)
//   [0.5M , 1M  )  Kp [b][n][8] bf16
//   [1M   , 5M  )  Vf [b][jt64][kstep4][chalf2][lane64][e8] bf16 (8KB/slab, pi order)
//   [5M   , 5.5M)  Lpart [js4][b][n] fp32
//   [6M   , 22M )  Opart [js4][b][n][c] bf16

#define N_ 4096
#define LOG2E 1.4426950408889634f

typedef __attribute__((ext_vector_type(8)))  __bf16 bf16x8;
typedef __attribute__((ext_vector_type(4)))  float  f32x4;
typedef __attribute__((ext_vector_type(16))) float  f32x16;

union U16B { uint4 u; bf16x8 b; };

static __device__ inline uint pack_bf2(float a, float b) {
  __hip_bfloat162 h = __float22bfloat162_rn(make_float2(a, b));
  uint r; __builtin_memcpy(&r, &h, 4); return r;
}
static __device__ inline ushort f2bf(float a) {
  __hip_bfloat16 h = __float2bfloat16(a);
  ushort r; __builtin_memcpy(&r, &h, 2); return r;
}
static __device__ inline float bflo(uint u) {
  uint v = u << 16; float f; __builtin_memcpy(&f, &v, 4); return f;
}
static __device__ inline float bfhi(uint u) {
  uint v = u & 0xffff0000u; float f; __builtin_memcpy(&f, &v, 4); return f;
}

// ---------------- pass 1: fused transpose + projection ----------------
__global__ __launch_bounds__(256) void prep_kernel(
    const float* __restrict__ x,  const float* __restrict__ Wf,
    const float* __restrict__ Wg, const float* __restrict__ Wh,
    ushort* __restrict__ Qp, ushort* __restrict__ Kp, ushort* __restrict__ Vf)
{
  __shared__ __align__(16) char smem[37376];
  float*  T   = (float*)smem;              // 64x65 fp32 x-tile (reused as Vt 8KB)
  ushort* xTl = (ushort*)(smem + 16640);   // 64n x 72c bf16
  ushort* Wb  = (ushort*)(smem + 25856);   // 80 x 72 bf16
  const int b = blockIdx.y, n0 = blockIdx.x * 64, tid = threadIdx.x;

  { // stage x tile (coalesced by n)
    const int nl = tid & 63, cw = tid >> 6;
#pragma unroll
    for (int i = 0; i < 16; ++i) {
      const int c = i * 4 + cw;
      T[c * 65 + nl] = x[((size_t)(b * 64 + c)) * N_ + n0 + nl];
    }
  }
  { // stage weights
#pragma unroll
    for (int i = 0; i < 20; ++i) {
      const int e = i * 256 + tid;
      const int row = e >> 6, col = e & 63;
      float v;
      if (row < 8)       v = Wf[row * 64 + col] * LOG2E;
      else if (row < 16) v = Wg[(row - 8) * 64 + col];
      else               v = Wh[(row - 16) * 64 + col];
      Wb[row * 72 + col] = f2bf(v);
    }
  }
  __syncthreads();
  { // transpose to xTl [n][c] bf16
    const int n = tid >> 2, cq = (tid & 3) * 16;
    uint o[8];
#pragma unroll
    for (int j = 0; j < 8; ++j)
      o[j] = pack_bf2(T[(cq + 2 * j) * 65 + n], T[(cq + 2 * j + 1) * 65 + n]);
    *(uint4*)(xTl + n * 72 + cq)     = make_uint4(o[0], o[1], o[2], o[3]);
    *(uint4*)(xTl + n * 72 + cq + 8) = make_uint4(o[4], o[5], o[6], o[7]);
  }
  __syncthreads();

  const int l = tid & 63, w = tid >> 6, l15 = l & 15, lq = l >> 4;
  const int nn = w * 16 + l15;
  U16B bf0, bf1;
  bf0.u = *(const uint4*)(xTl + nn * 72 + lq * 8);
  bf1.u = *(const uint4*)(xTl + nn * 72 + 32 + lq * 8);
  f32x4 acc[5];
#pragma unroll
  for (int mt = 0; mt < 5; ++mt) {
    U16B a0, a1;
    a0.u = *(const uint4*)(Wb + (mt * 16 + l15) * 72 + lq * 8);
    a1.u = *(const uint4*)(Wb + (mt * 16 + l15) * 72 + 32 + lq * 8);
    f32x4 c0 = __builtin_amdgcn_mfma_f32_16x16x32_bf16(a0.b, bf0.b, (f32x4){0.f,0.f,0.f,0.f}, 0, 0, 0);
    acc[mt]  = __builtin_amdgcn_mfma_f32_16x16x32_bf16(a1.b, bf1.b, c0, 0, 0, 0);
  }
  const int n = n0 + nn;
  { // rows 0-7 -> Q, 8-15 -> K  (C: col=n=l15, row=lq*4+r)
    uint lo = pack_bf2(acc[0][0], acc[0][1]);
    uint hi = pack_bf2(acc[0][2], acc[0][3]);
    ushort* dst = (lq < 2 ? Qp : Kp) + ((size_t)(b * N_ + n)) * 8 + (lq & 1) * 4;
    *(uint2*)dst = make_uint2(lo, hi);
  }
  // V -> pi-permuted fragment-linear LDS slab (overwrites T; T dead)
  ushort* Vt = (ushort*)smem;
  const int jp = nn;                       // j within tile, 0..63
  const int jl = jp & 31, stp = (jl >> 4) & 1, j16 = jl & 15;
  const int s  = (j16 & 3) | ((j16 & 4) << 1) | ((j16 & 8) >> 1);  // inverse-pi slot
  const int vbase = ((jp >> 5) * 2 + stp) * 1024 + (s >> 3) * 256 + (s & 7);
#pragma unroll
  for (int mt = 1; mt < 5; ++mt)
#pragma unroll
    for (int r = 0; r < 4; ++r) {
      const int c = (mt - 1) * 16 + lq * 4 + r;
      Vt[vbase + (c >> 5) * 512 + (c & 31) * 8] = f2bf(acc[mt][r]);
    }
  __syncthreads();
  const uint4* src = (const uint4*)Vt;
  uint4* dst = (uint4*)(Vf + ((size_t)(b * 64 + blockIdx.x)) * 4096);
  dst[tid]       = src[tid];
  dst[256 + tid] = src[256 + tid];
}

// ---------------- pass 2: flash attention, j-split x4 ----------------
// grid (16 qblk, 4 js, 8 b), 256 thr, 64 q/wave, 16 j-tiles of 64 per block.
__global__ __launch_bounds__(256) void attn_kernel(
    const ushort* __restrict__ Qp, const ushort* __restrict__ Kp,
    const ushort* __restrict__ Vf,
    ushort* __restrict__ Opart, float* __restrict__ Lpart)
{
  __shared__ __align__(16) uint4 vsl[1024];   // 2 slabs x 8KB
  const int b = blockIdx.z, js = blockIdx.y;
  const int tid = threadIdx.x, w = tid >> 6, l = tid & 63;
  const int l31 = l & 31, lq1 = l >> 5;
  const int q0w = blockIdx.x * 256 + w * 64;
  const uint4 zero4 = make_uint4(0u, 0u, 0u, 0u);

  U16B qf[2];   // B-frags: lanes 0-31 real (k=d 0..7), lanes 32-63 zero (d 8..15)
#pragma unroll
  for (int qc = 0; qc < 2; ++qc)
    qf[qc].u = lq1 ? zero4
        : *(const uint4*)(Qp + ((size_t)(b * N_ + q0w + qc * 32 + l31)) * 8);

  const int jb0 = js * 1024;
  U16B kf[2], kfn[2];
#pragma unroll
  for (int jc = 0; jc < 2; ++jc)
    kf[jc].u = lq1 ? zero4
        : *(const uint4*)(Kp + ((size_t)(b * N_ + jb0 + jc * 32 + l31)) * 8);

  const uint4* Vg = (const uint4*)(Vf + ((size_t)(b * 64 + js * 16)) * 4096);
  vsl[tid]       = Vg[tid];
  vsl[256 + tid] = Vg[256 + tid];

  const f32x16 Oz = {0,0,0,0,0,0,0,0,0,0,0,0,0,0,0,0};
  f32x16 O[2][2] = {{Oz, Oz}, {Oz, Oz}};   // [qc][chalf]
  float L0 = 0.f, L1 = 0.f;
  uint pk[2][2][8];                        // [qc][jc][dword]
  uint4 vp0, vp1;
  int p = 0;
  __syncthreads();

  for (int jt = 0; jt < 16; ++jt) {
    if (jt < 15) {  // register prefetch: next V slab + next K frags
      vp0 = Vg[(jt + 1) * 512 + tid];
      vp1 = Vg[(jt + 1) * 512 + 256 + tid];
#pragma unroll
      for (int jc = 0; jc < 2; ++jc)
        kfn[jc].u = lq1 ? zero4
            : *(const uint4*)(Kp + ((size_t)(b * N_ + jb0 + (jt + 1) * 64 + jc * 32 + l31)) * 8);
    }
    // S^T = K*Q^T via 32x32x16: lane -> col q=l31, rows j=(r&3)+8*(r>>2)+4*lq1
#pragma unroll
    for (int qc = 0; qc < 2; ++qc)
#pragma unroll
      for (int jc = 0; jc < 2; ++jc) {
        f32x16 St = __builtin_amdgcn_mfma_f32_32x32x16_bf16(
            kf[jc].b, qc ? qf[1].b : qf[0].b, Oz, 0, 0, 0);
        float e[16];
#pragma unroll
        for (int r = 0; r < 16; ++r) e[r] = __builtin_amdgcn_exp2f(St[r]);
        const float ps = (((e[0] + e[1]) + (e[2] + e[3])) + ((e[4] + e[5]) + (e[6] + e[7])))
                       + (((e[8] + e[9]) + (e[10] + e[11])) + ((e[12] + e[13]) + (e[14] + e[15])));
        if (qc) L1 += ps; else L0 += ps;
#pragma unroll
        for (int d = 0; d < 8; ++d) pk[qc][jc][d] = pack_bf2(e[2 * d], e[2 * d + 1]);
      }
    // O += P*V: P A-frags straight from pk (pi handled by Vf layout)
    const uint4* vb = vsl + p * 512;
#pragma unroll
    for (int ks = 0; ks < 4; ++ks) {
      const int jc = ks >> 1, st = (ks & 1) * 4;
#pragma unroll
      for (int ch = 0; ch < 2; ++ch) {
        U16B vfr; vfr.u = vb[ks * 128 + ch * 64 + l];
#pragma unroll
        for (int qc = 0; qc < 2; ++qc) {
          U16B pa;
          pa.u = make_uint4(pk[qc][jc][st], pk[qc][jc][st + 1],
                            pk[qc][jc][st + 2], pk[qc][jc][st + 3]);
          O[qc][ch] = __builtin_amdgcn_mfma_f32_32x32x16_bf16(pa.b, vfr.b, O[qc][ch], 0, 0, 0);
        }
      }
    }
    if (jt < 15) {  // stage prefetched slab into the other buffer
      vsl[(p ^ 1) * 512 + tid]       = vp0;
      vsl[(p ^ 1) * 512 + 256 + tid] = vp1;
#pragma unroll
      for (int jc = 0; jc < 2; ++jc) kf[jc] = kfn[jc];
    }
    __syncthreads();
    p ^= 1;
  }

  // partial denominators: lane halves (lq1) hold disjoint j for same q
  L0 += __shfl_xor(L0, 32);
  L1 += __shfl_xor(L1, 32);
  float* Lp = Lpart + ((size_t)(js * 8 + b)) * N_;
  if (lq1 == 0) {
    Lp[q0w + l31]      = L0;
    Lp[q0w + 32 + l31] = L1;
  }

  // partial O: row q = qc*32 + (r&3)+8*(r>>2)+4*lq1, col c = ch*32 + l31
  ushort* Op = Opart + (((size_t)(js * 8 + b)) * N_ + q0w) * 64;
#pragma unroll
  for (int qc = 0; qc < 2; ++qc)
#pragma unroll
    for (int ch = 0; ch < 2; ++ch)
#pragma unroll
      for (int g = 0; g < 4; ++g)
#pragma unroll
        for (int r = 0; r < 4; ++r) {
          const int q = qc * 32 + r + 8 * g + 4 * lq1;
          Op[q * 64 + ch * 32 + l31] = f2bf(O[qc][ch][g * 4 + r]);
        }
}

// ---------------- pass 3: combine partials + normalize + gamma*o + x ----------------
__global__ __launch_bounds__(256) void combine_kernel(
    const ushort* __restrict__ Opart, const float* __restrict__ Lpart,
    const float* __restrict__ x, const float* __restrict__ gamma,
    float* __restrict__ out)
{
  __shared__ float T[64 * 65];
  const int b = blockIdx.y, n0 = blockIdx.x * 64, tid = threadIdx.x;
  float acc[16];
#pragma unroll
  for (int e = 0; e < 16; ++e) acc[e] = 0.f;
#pragma unroll
  for (int js = 0; js < 4; ++js) {
    const ushort* Op = Opart + (((size_t)(js * 8 + b)) * N_ + n0) * 64 + tid * 16;
    uint4 a  = *(const uint4*)Op;
    uint4 c2 = *(const uint4*)(Op + 8);
    acc[0] += bflo(a.x);  acc[1] += bfhi(a.x);  acc[2] += bflo(a.y);  acc[3] += bfhi(a.y);
    acc[4] += bflo(a.z);  acc[5] += bfhi(a.z);  acc[6] += bflo(a.w);  acc[7] += bfhi(a.w);
    acc[8] += bflo(c2.x); acc[9] += bfhi(c2.x); acc[10]+= bflo(c2.y); acc[11]+= bfhi(c2.y);
    acc[12]+= bflo(c2.z); acc[13]+= bfhi(c2.z); acc[14]+= bflo(c2.w); acc[15]+= bfhi(c2.w);
  }
  const int nr = tid >> 2, c0 = (tid & 3) * 16;
#pragma unroll
  for (int e = 0; e < 16; ++e) T[nr * 65 + c0 + e] = acc[e];
  __syncthreads();
  const float g = gamma[0];
  const int n = tid & 63, cq = (tid >> 6) * 16;
  float Ls = 0.f;
#pragma unroll
  for (int js = 0; js < 4; ++js) Ls += Lpart[((size_t)(js * 8 + b)) * N_ + n0 + n];
  const float gr = g / Ls;
#pragma unroll
  for (int i = 0; i < 16; ++i) {
    const int c = cq + i;
    const size_t oi = ((size_t)(b * 64 + c)) * N_ + n0 + n;
    out[oi] = gr * T[n * 65 + c] + x[oi];
  }
}

extern "C" void kernel_launch(void* const* d_in, const int* in_sizes, int n_in,
                              void* d_out, int out_size, void* d_ws, size_t ws_size,
                              hipStream_t stream) {
  const float* x     = (const float*)d_in[0];
  const float* Wf    = (const float*)d_in[1];
  const float* Wg    = (const float*)d_in[2];
  const float* Wh    = (const float*)d_in[3];
  const float* gamma = (const float*)d_in[4];
  float* out = (float*)d_out;
  char* ws = (char*)d_ws;

  ushort* Qp    = (ushort*)(ws);
  ushort* Kp    = (ushort*)(ws + 512 * 1024);
  ushort* Vf    = (ushort*)(ws + 1024 * 1024);       // 4 MB
  float*  Lpart = (float*) (ws + 5 * 1024 * 1024);   // 512 KB
  ushort* Opart = (ushort*)(ws + 6 * 1024 * 1024);   // 16 MB

  prep_kernel   <<<dim3(64, 8),    256, 0, stream>>>(x, Wf, Wg, Wh, Qp, Kp, Vf);
  attn_kernel   <<<dim3(16, 4, 8), 256, 0, stream>>>(Qp, Kp, Vf, Opart, Lpart);
  combine_kernel<<<dim3(64, 8),    256, 0, stream>>>(Opart, Lpart, x, gamma, out);
}